// Round 18
// baseline (1166.128 us; speedup 1.0000x reference)
//
#include <hip/hip_runtime.h>
#include <hip/hip_bf16.h>
#include <math.h>

#define N_NODES 40000
#define N_EDGES 640000
#define DIM     128
#define HEADS   8
#define DHEAD   16
#define LAYERS  3
#define IN_DIM  64
#define FF_DIM  218
#define BN_EPS  1e-5f
#define NEG_SLOPE 0.2f
#define INV_N   (1.f / N_NODES)
#define NREP    128

typedef __attribute__((ext_vector_type(8))) short  bhalf8;
typedef __attribute__((ext_vector_type(4))) float  floatx4;
typedef __attribute__((ext_vector_type(4))) int    intx4;

__device__ __forceinline__ unsigned bfpack2(float a, float b) {
    unsigned ua = __float_as_uint(a);
    ua = ua + 0x7FFFu + ((ua >> 16) & 1u);
    unsigned ub = __float_as_uint(b);
    ub = ub + 0x7FFFu + ((ub >> 16) & 1u);
    return (ua >> 16) | (ub & 0xFFFF0000u);
}
__device__ __forceinline__ unsigned short bf16of(float a) {
    unsigned ua = __float_as_uint(a);
    ua = ua + 0x7FFFu + ((ua >> 16) & 1u);
    return (unsigned short)(ua >> 16);
}
__device__ __forceinline__ float bf2f(unsigned short u) {
    return __uint_as_float(((unsigned)u) << 16);
}
__device__ __forceinline__ float bflo(unsigned u) { return __uint_as_float(u << 16); }
__device__ __forceinline__ float bfhi(unsigned u) { return __uint_as_float(u & 0xFFFF0000u); }
__device__ __forceinline__ float rsum16(float v) {
    v += __shfl_xor(v, 1, 16);
    v += __shfl_xor(v, 2, 16);
    v += __shfl_xor(v, 4, 16);
    v += __shfl_xor(v, 8, 16);
    return v;
}

// packed weight layout offsets (bf16 elements)
#define OFF_EMB 0
#define OFF_GAT 8192
#define OFF_W1  57344
#define OFF_W2  143360
#define OFF_DEC 229376
#define WPK_TOT 294912
#define HIST_BLOCKS ((N_EDGES + 255) / 256)
#define PACK_BLOCKS ((WPK_TOT + 255) / 256)

// ---------------------------------------------------------------- hist + weight pre-pack (merged)
__global__ void hist_pack_kernel(const int* __restrict__ dst, int* __restrict__ counts,
                                 const float* __restrict__ W_emb,
                                 const float* __restrict__ gat_W,
                                 const float* __restrict__ ff_W1,
                                 const float* __restrict__ ff_W2,
                                 const float* __restrict__ dec_W1,
                                 unsigned short* __restrict__ wpk) {
    int bid = blockIdx.x;
    if (bid < HIST_BLOCKS) {
        int e = bid * 256 + threadIdx.x;
        if (e < N_EDGES) atomicAdd(&counts[dst[e]], 1);
        return;
    }
    int i = (bid - HIST_BLOCKS) * 256 + threadIdx.x;
    if (i >= WPK_TOT) return;
    int o = i;
    if (o < 8192) {                       // emb: [128][64]
        int n = o >> 6, k = o & 63;
        wpk[OFF_EMB + o] = bf16of(W_emb[k * 128 + n]);
        return;
    }
    o -= 8192;
    if (o < 3 * 16384) {                  // gat: [l][128][128]
        int l = o >> 14, r = o & 16383;
        int n = r >> 7, k = r & 127;
        wpk[OFF_GAT + o] = bf16of(gat_W[l * 16384 + k * 128 + n]);
        return;
    }
    o -= 3 * 16384;
    if (o < 3 * 28672) {                  // W1: [l][224][128]
        int l = o / 28672, r = o % 28672;
        int n = r >> 7, k = r & 127;
        float v = (n < FF_DIM) ? ff_W1[(size_t)l * 128 * FF_DIM + k * FF_DIM + n] : 0.f;
        wpk[OFF_W1 + o] = bf16of(v);
        return;
    }
    o -= 3 * 28672;
    if (o < 3 * 28672) {                  // W2: [l][128][224]
        int l = o / 28672, r = o % 28672;
        int n = r / 224, k = r % 224;
        float v = (k < FF_DIM) ? ff_W2[(size_t)l * FF_DIM * 128 + k * 128 + n] : 0.f;
        wpk[OFF_W2 + o] = bf16of(v);
        return;
    }
    o -= 3 * 28672;
    {                                     // dec: [128][512]
        int n = o >> 9, k = o & 511;
        wpk[OFF_DEC + o] = bf16of(dec_W1[k * 128 + n]);
    }
}

// ---------------------------------------------------------------- CSR build
__global__ __launch_bounds__(1024) void scan_kernel(const int* __restrict__ counts,
                                                    int* __restrict__ indptr,
                                                    int* __restrict__ cursor, int n) {
    __shared__ int tsum[1024];
    const int CH = 40;
    int tid = threadIdx.x;
    int base = tid * CH;
    int loc[CH];
    int s = 0;
    #pragma unroll
    for (int i = 0; i < CH; i++) {
        int idx = base + i;
        int v = (idx < n) ? counts[idx] : 0;
        loc[i] = s;
        s += v;
    }
    tsum[tid] = s;
    __syncthreads();
    for (int offs = 1; offs < 1024; offs <<= 1) {
        int t = (tid >= offs) ? tsum[tid - offs] : 0;
        __syncthreads();
        tsum[tid] += t;
        __syncthreads();
    }
    int carry = (tid > 0) ? tsum[tid - 1] : 0;
    #pragma unroll
    for (int i = 0; i < CH; i++) {
        int idx = base + i;
        if (idx < n) {
            int v = carry + loc[i];
            indptr[idx] = v;
            cursor[idx] = v;
        }
    }
    if (tid == 1023) indptr[n] = tsum[1023];
}

__global__ void scatter_kernel(const int* __restrict__ src, const int* __restrict__ dst,
                               int* __restrict__ cursor,
                               int* __restrict__ srcs_csr) {
    int e = blockIdx.x * blockDim.x + threadIdx.x;
    if (e < N_EDGES) {
        int d = dst[e];
        int pos = atomicAdd(&cursor[d], 1);
        srcs_csr[pos] = src[e];
    }
}

// ---------------------------------------------------------------- split-K L2-resident-B GEMM
// Block = 4 waves over a 32-row x NT*16-col tile; wave w computes K-slice
// [w*SH, (w+1)*SH) of STEPS; partials reduced via LDS (waves 2,3 -> 0,1 -> 0);
// wave 0 runs the fused epilogue. 4x the blocks of r17 at identical HBM traffic.
// AMODE: 0 none; 1 BN affine on A; 2 dec512 layered affine; 3 NREP-replica stats.
template<int NT, int KPAD, int AMODE, bool ABF16, bool ELER, bool RESBF>
__global__ __launch_bounds__(256) void gemm_sk_kernel(
    const float* __restrict__ A, const unsigned short* __restrict__ Abf, int lda,
    const unsigned short* __restrict__ Bpk,
    const float* __restrict__ bias,
    const void* __restrict__ resv, int ldres,
    const float* __restrict__ res_stats, const float* __restrict__ res_g,
    const float* __restrict__ res_b,
    float* __restrict__ C, unsigned short* __restrict__ Cbf, int ldc,
    float* __restrict__ out_stats,
    int M, int Nact, int relu,
    const float* __restrict__ a_stats, float* __restrict__ a_stats_out,
    const float* __restrict__ a_g, const float* __restrict__ a_b,
    const float* __restrict__ al, const float* __restrict__ ar,
    float* __restrict__ el_out, float* __restrict__ er_out)
{
    constexpr int MT = 2;
    constexpr int SCN = (AMODE > 0) ? KPAD : 1;
    constexpr int STEPS = KPAD / 32;
    constexpr int SH = (STEPS + 3) / 4;          // k-steps per wave
    constexpr int CSTk = (SH > 2) ? 2 : SH;
    __shared__ float sc_s[SCN];
    __shared__ float sh_s[SCN];
    __shared__ float st_sum[128];
    __shared__ float st_sq[128];
    __shared__ float part[2][MT * NT * 4][64];
    __shared__ float el_s[ELER ? 32 : 1][ELER ? NT : 1];
    __shared__ float er_s[ELER ? 32 : 1][ELER ? NT : 1];

    int tid = threadIdx.x, wave = tid >> 6, lane = tid & 63;
    int q = lane >> 4, tl = lane & 15;
    int colbase = blockIdx.y * (NT * 16);
    int rowtile = blockIdx.x * 32;

    if (out_stats && tid < 128) { st_sum[tid] = 0.f; st_sq[tid] = 0.f; }

    if constexpr (AMODE == 1 || AMODE == 2) {
        for (int idx = tid; idx < KPAD; idx += 256) {
            float scv = 1.f, shv = 0.f;
            if constexpr (AMODE == 1) {
                float mu = a_stats[idx] * INV_N;
                float var = a_stats[128 + idx] * INV_N - mu * mu;
                scv = a_g[idx] * rsqrtf(var + BN_EPS);
                shv = a_b[idx] - mu * scv;
            } else {
                int l = idx >> 7;
                if (l > 0) {
                    int c = idx & 127;
                    const float* st = a_stats + (l - 1) * 256;
                    float mu = st[c] * INV_N;
                    float var = st[128 + c] * INV_N - mu * mu;
                    scv = a_g[(l - 1) * 128 + c] * rsqrtf(var + BN_EPS);
                    shv = a_b[(l - 1) * 128 + c] - mu * scv;
                }
            }
            sc_s[idx] = scv;
            sh_s[idx] = shv;
        }
        __syncthreads();
    }
    if constexpr (AMODE == 3) {
        for (int idx = tid; idx < 128; idx += 256) {
            float s = 0.f, sq = 0.f;
            #pragma unroll 8
            for (int r = 0; r < NREP; r++) {
                s  += a_stats[r * 256 + idx];
                sq += a_stats[r * 256 + 128 + idx];
            }
            a_stats_out[idx] = s;            // benign identical-value race
            a_stats_out[128 + idx] = sq;
            float mu = s * INV_N;
            float var = sq * INV_N - mu * mu;
            float scv = a_g[idx] * rsqrtf(var + BN_EPS);
            sc_s[idx] = scv;
            sh_s[idx] = a_b[idx] - mu * scv;
        }
        __syncthreads();
    }

    int rowm[MT];
    bool vrm[MT];
    #pragma unroll
    for (int mt = 0; mt < MT; mt++) {
        rowm[mt] = rowtile + mt * 16 + tl;
        vrm[mt] = rowm[mt] < M;
    }
    const unsigned short* bp = Bpk + (size_t)colbase * KPAD;

    floatx4 acc[MT][NT] = {};
    int sbeg = wave * SH;

    #pragma unroll
    for (int c0o = 0; c0o < SH; c0o += CSTk) {
        intx4  arawb[CSTk][MT];
        floatx4 araw0[ABF16 ? 1 : CSTk][ABF16 ? 1 : MT];
        floatx4 araw1[ABF16 ? 1 : CSTk][ABF16 ? 1 : MT];
        bhalf8 breg[CSTk][NT];
        bool actv[CSTk];
        int gks[CSTk];
        #pragma unroll
        for (int cs = 0; cs < CSTk; cs++) {
            if (c0o + cs >= SH) { actv[cs] = false; gks[cs] = q * 8; continue; }
            int s = sbeg + c0o + cs;
            bool act = s < STEPS;          // wave-uniform
            actv[cs] = act;
            int gk = (act ? s : 0) * 32 + q * 8;
            gks[cs] = gk;
            #pragma unroll
            for (int j = 0; j < NT; j++)
                breg[cs][j] = *(const bhalf8*)(bp + (size_t)(j * 16 + tl) * KPAD + gk);
            #pragma unroll
            for (int mt = 0; mt < MT; mt++) {
                if constexpr (ABF16) {
                    intx4 u = {};
                    if (act && vrm[mt]) u = *(const intx4*)(Abf + (size_t)rowm[mt] * lda + gk);
                    arawb[cs][mt] = u;
                } else {
                    floatx4 x0 = {}, x1 = {};
                    if (act && vrm[mt]) {
                        const float* ap = A + (size_t)rowm[mt] * lda + gk;
                        x0 = *(const floatx4*)ap;
                        x1 = *(const floatx4*)(ap + 4);
                    }
                    araw0[cs][mt] = x0;
                    araw1[cs][mt] = x1;
                }
            }
        }
        #pragma unroll
        for (int cs = 0; cs < CSTk; cs++) {
            if (c0o + cs >= SH) continue;
            if (!actv[cs]) continue;       // wave-uniform branch
            int gk = gks[cs];
            bhalf8 af[MT];
            #pragma unroll
            for (int mt = 0; mt < MT; mt++) {
                if constexpr (ABF16) {
                    intx4 u = arawb[cs][mt];
                    if constexpr (AMODE > 0) {
                        #pragma unroll
                        for (int w = 0; w < 4; w++) {
                            unsigned uw = (unsigned)u[w];
                            float lo = bflo(uw), hi = bfhi(uw);
                            lo = fmaf(sc_s[gk + 2 * w],     lo, sh_s[gk + 2 * w]);
                            hi = fmaf(sc_s[gk + 2 * w + 1], hi, sh_s[gk + 2 * w + 1]);
                            u[w] = (int)bfpack2(lo, hi);
                        }
                    }
                    af[mt] = *(bhalf8*)&u;
                } else {
                    floatx4 x0 = araw0[cs][mt], x1 = araw1[cs][mt];
                    if constexpr (AMODE > 0) {
                        #pragma unroll
                        for (int jj = 0; jj < 4; jj++) {
                            x0[jj] = fmaf(sc_s[gk + jj],     x0[jj], sh_s[gk + jj]);
                            x1[jj] = fmaf(sc_s[gk + 4 + jj], x1[jj], sh_s[gk + 4 + jj]);
                        }
                    }
                    intx4 t = intx4{(int)bfpack2(x0[0], x0[1]), (int)bfpack2(x0[2], x0[3]),
                                    (int)bfpack2(x1[0], x1[1]), (int)bfpack2(x1[2], x1[3])};
                    af[mt] = *(bhalf8*)&t;
                }
            }
            #pragma unroll
            for (int mt = 0; mt < MT; mt++)
                #pragma unroll
                for (int j = 0; j < NT; j++)
                    acc[mt][j] = __builtin_amdgcn_mfma_f32_16x16x32_bf16(af[mt], breg[cs][j], acc[mt][j], 0, 0, 0);
        }
    }

    // ---- staged LDS reduce: waves 2,3 -> waves 0,1; wave 1 -> wave 0
    #define PIDX(mt, j, reg) ((mt) * NT * 4 + (j) * 4 + (reg))
    if (wave >= 2) {
        int slot = wave - 2;
        #pragma unroll
        for (int mt = 0; mt < MT; mt++)
            #pragma unroll
            for (int j = 0; j < NT; j++)
                #pragma unroll
                for (int reg = 0; reg < 4; reg++)
                    part[slot][PIDX(mt, j, reg)][lane] = acc[mt][j][reg];
    }
    __syncthreads();
    if (wave < 2) {
        #pragma unroll
        for (int mt = 0; mt < MT; mt++)
            #pragma unroll
            for (int j = 0; j < NT; j++)
                #pragma unroll
                for (int reg = 0; reg < 4; reg++)
                    acc[mt][j][reg] += part[wave][PIDX(mt, j, reg)][lane];
    }
    __syncthreads();
    if (wave == 1) {
        #pragma unroll
        for (int mt = 0; mt < MT; mt++)
            #pragma unroll
            for (int j = 0; j < NT; j++)
                #pragma unroll
                for (int reg = 0; reg < 4; reg++)
                    part[0][PIDX(mt, j, reg)][lane] = acc[mt][j][reg];
    }
    __syncthreads();

    if (wave == 0) {
        #pragma unroll
        for (int mt = 0; mt < MT; mt++)
            #pragma unroll
            for (int j = 0; j < NT; j++)
                #pragma unroll
                for (int reg = 0; reg < 4; reg++)
                    acc[mt][j][reg] += part[0][PIDX(mt, j, reg)][lane];

        // ---- epilogue (wave 0 only): C/D layout col=lane&15, row=quad*4+reg
        float psum[NT], psq[NT];
        #pragma unroll
        for (int j = 0; j < NT; j++) { psum[j] = 0.f; psq[j] = 0.f; }

        #pragma unroll
        for (int j = 0; j < NT; j++) {
            int c = colbase + j * 16 + tl;
            bool cok = c < Nact;
            float bv = (bias && cok) ? bias[c] : 0.f;
            float rsc = 1.f, rsh = 0.f;
            if (res_stats && cok) {
                float mu = res_stats[c] * INV_N;
                float var = res_stats[128 + c] * INV_N - mu * mu;
                rsc = res_g[c] * rsqrtf(var + BN_EPS);
                rsh = res_b[c] - mu * rsc;
            }
            float alc = 0.f, arc = 0.f;
            if constexpr (ELER) { alc = al[c]; arc = ar[c]; }
            #pragma unroll
            for (int mt = 0; mt < MT; mt++) {
                #pragma unroll
                for (int reg = 0; reg < 4; reg++) {
                    int r = rowtile + mt * 16 + q * 4 + reg;
                    bool rok = r < M;
                    float v = 0.f;
                    if (rok && cok) {
                        v = acc[mt][j][reg] + bv;
                        if (resv) {
                            size_t ri = (size_t)r * ldres + c;
                            float rv = RESBF ? bf2f(((const unsigned short*)resv)[ri])
                                             : ((const float*)resv)[ri];
                            v = fmaf(rsc, rv, v + rsh);
                        }
                        if (relu) v = fmaxf(v, 0.f);
                        if (out_stats) { psum[j] += v; psq[j] = fmaf(v, v, psq[j]); }
                    }
                    if constexpr (ELER) {
                        float pel = rsum16(v * alc);
                        float per_ = rsum16(v * arc);
                        if (tl == 0) {
                            int rl = mt * 16 + q * 4 + reg;
                            el_s[rl][j] = pel;
                            er_s[rl][j] = per_;
                        }
                    }
                    if (rok) {
                        if (Cbf) Cbf[(size_t)r * ldc + c] = bf16of(v);
                        else if (cok) C[(size_t)r * ldc + c] = v;
                    }
                }
            }
        }
        if (out_stats) {
            #pragma unroll
            for (int j = 0; j < NT; j++) {
                int c = colbase + j * 16 + tl;
                if (c < 128) { atomicAdd(&st_sum[c], psum[j]); atomicAdd(&st_sq[c], psq[j]); }
            }
        }
    }

    if (ELER || out_stats) __syncthreads();
    if constexpr (ELER) {
        int gh = blockIdx.y * NT;
        for (int idx = tid; idx < 32 * NT; idx += 256) {
            int rl = idx / NT, hj = idx % NT;
            int r = rowtile + rl;
            if (r < M) {
                el_out[(size_t)r * 8 + gh + hj] = el_s[rl][hj];
                er_out[(size_t)r * 8 + gh + hj] = er_s[rl][hj];
            }
        }
    }
    if (out_stats && tid < 128) {
        atomicAdd(&out_stats[tid], st_sum[tid]);
        atomicAdd(&out_stats[128 + tid], st_sq[tid]);
    }
    #undef PIDX
}

// ---------------------------------------------------------------- GAT aggregate
// Round-14 structure (measured best): 1 node/block, 4 edge-groups x 4-unroll =
// 16 gathers in flight; fused BN1 stats into NREP-replica buffers.
__global__ __launch_bounds__(256) void gat_aggregate_kernel(
    const unsigned short* __restrict__ feat,
    const float* __restrict__ el, const float* __restrict__ er,
    const int* __restrict__ indptr, const int* __restrict__ srcs_csr,
    const unsigned short* __restrict__ h_in, int ldh,
    const float* __restrict__ hstats, const float* __restrict__ hg,
    const float* __restrict__ hb,
    const float* __restrict__ bias,
    unsigned short* __restrict__ outp,
    float* __restrict__ stats_rep)
{
    int n = blockIdx.x;
    int t = threadIdx.x;
    int p = t >> 6;
    int lane = t & 63;
    int d0 = lane * 2;
    int hh = lane >> 3;
    int pick = lane & 3;
    int gb = lane & 56;
    __shared__ float red[4][128];
    __shared__ float denh[4][HEADS];
    int beg = indptr[n], end = indptr[n + 1];
    float ern = er[(size_t)n * 8 + hh];

    float acc0 = 0.f, acc1 = 0.f, den = 0.f;
    int i = beg + p;
    for (; i + 12 < end; i += 16) {
        int s0 = srcs_csr[i],     s1 = srcs_csr[i + 4];
        int s2 = srcs_csr[i + 8], s3 = srcs_csr[i + 12];
        int sp = pick == 0 ? s0 : pick == 1 ? s1 : pick == 2 ? s2 : s3;
        float ee = el[(size_t)sp * 8 + hh] + ern;
        unsigned f0 = *(const unsigned*)(feat + (size_t)s0 * DIM + d0);
        unsigned f1 = *(const unsigned*)(feat + (size_t)s1 * DIM + d0);
        unsigned f2 = *(const unsigned*)(feat + (size_t)s2 * DIM + d0);
        unsigned f3 = *(const unsigned*)(feat + (size_t)s3 * DIM + d0);
        float aa = expf(ee > 0.f ? ee : NEG_SLOPE * ee);
        float a0 = __shfl(aa, gb + 0);
        float a1 = __shfl(aa, gb + 1);
        float a2 = __shfl(aa, gb + 2);
        float a3 = __shfl(aa, gb + 3);
        den += (a0 + a1) + (a2 + a3);
        acc0 = fmaf(a0, bflo(f0), acc0); acc1 = fmaf(a0, bfhi(f0), acc1);
        acc0 = fmaf(a1, bflo(f1), acc0); acc1 = fmaf(a1, bfhi(f1), acc1);
        acc0 = fmaf(a2, bflo(f2), acc0); acc1 = fmaf(a2, bfhi(f2), acc1);
        acc0 = fmaf(a3, bflo(f3), acc0); acc1 = fmaf(a3, bfhi(f3), acc1);
    }
    for (; i < end; i += 4) {
        int s0 = srcs_csr[i];
        float e0 = el[(size_t)s0 * 8 + hh] + ern;
        unsigned f0 = *(const unsigned*)(feat + (size_t)s0 * DIM + d0);
        float a0 = expf(e0 > 0.f ? e0 : NEG_SLOPE * e0);
        den += a0;
        acc0 = fmaf(a0, bflo(f0), acc0);
        acc1 = fmaf(a0, bfhi(f0), acc1);
    }
    red[p][d0] = acc0;
    red[p][d0 + 1] = acc1;
    if ((lane & 7) == 0) denh[p][hh] = den;
    __syncthreads();
    if (t < 128) {
        int d = t, h = d >> 4;
        float tot = (red[0][d] + red[1][d]) + (red[2][d] + red[3][d]);
        float dtot = (denh[0][h] + denh[1][h]) + (denh[2][h] + denh[3][h]);
        float inv = dtot > 0.f ? 1.f / dtot : 0.f;
        float hv = bf2f(h_in[(size_t)n * ldh + d]);
        if (hstats) {
            float mu = hstats[d] * INV_N;
            float var = hstats[128 + d] * INV_N - mu * mu;
            float s = hg[d] * rsqrtf(var + BN_EPS);
            hv = fmaf(s, hv - mu, hb[d]);
        }
        unsigned short ub = bf16of(hv + tot * inv + bias[d]);
        outp[(size_t)n * DIM + d] = ub;
        float vr = bf2f(ub);
        float* rep = stats_rep + ((size_t)(n & (NREP - 1)) << 8);
        atomicAdd(&rep[d], vr);
        atomicAdd(&rep[128 + d], vr * vr);
    }
}

// ---------------------------------------------------------------- decision head
__global__ __launch_bounds__(256) void decide_kernel(
    const unsigned short* __restrict__ z, const float* __restrict__ stats,
    const float* __restrict__ g, const float* __restrict__ b,
    const float* __restrict__ W2, float* __restrict__ outp, int M)
{
    int wid = threadIdx.x >> 6, lane = threadIdx.x & 63;
    int n = blockIdx.x * 4 + wid;
    if (n >= M) return;
    float acc = 0.f;
    #pragma unroll
    for (int cc = 0; cc < 2; cc++) {
        int c = lane + cc * 64;
        float mu  = stats[c] * INV_N;
        float var = stats[DIM + c] * INV_N - mu * mu;
        float v = fmaf(g[c] * rsqrtf(var + BN_EPS), bf2f(z[(size_t)n * DIM + c]) - mu, b[c]);
        v = fmaxf(v, 0.f);
        acc = fmaf(v, W2[c], acc);
    }
    #pragma unroll
    for (int offs = 32; offs > 0; offs >>= 1)
        acc += __shfl_down(acc, offs);
    if (lane == 0) outp[n] = acc;
}

// ---------------------------------------------------------------- launch
extern "C" void kernel_launch(void* const* d_in, const int* in_sizes, int n_in,
                              void* d_out, int out_size, void* d_ws, size_t ws_size,
                              hipStream_t stream)
{
    const float* x      = (const float*)d_in[0];
    const int*   src    = (const int*)  d_in[1];
    const int*   dst    = (const int*)  d_in[2];
    const float* W_emb  = (const float*)d_in[3];
    const float* b_emb  = (const float*)d_in[4];
    const float* gat_W  = (const float*)d_in[5];
    const float* attn_l = (const float*)d_in[6];
    const float* attn_r = (const float*)d_in[7];
    const float* gat_b  = (const float*)d_in[8];
    const float* bn1_g  = (const float*)d_in[9];
    const float* bn1_b  = (const float*)d_in[10];
    const float* ff_W1  = (const float*)d_in[11];
    const float* ff_b1  = (const float*)d_in[12];
    const float* ff_W2  = (const float*)d_in[13];
    const float* ff_b2  = (const float*)d_in[14];
    const float* bn2_g  = (const float*)d_in[15];
    const float* bn2_b  = (const float*)d_in[16];
    const float* dec_W1 = (const float*)d_in[17];
    const float* dec_bn_g = (const float*)d_in[18];
    const float* dec_bn_b = (const float*)d_in[19];
    const float* dec_W2 = (const float*)d_in[20];
    float* outp = (float*)d_out;

    char* ws = (char*)d_ws;
    size_t off = 0;
    auto alloc = [&](size_t bytes) -> void* {
        void* p = ws + off;
        off += (bytes + 255) & ~(size_t)255;
        return p;
    };
    unsigned short* xsb = (unsigned short*)alloc((size_t)N_NODES * 512 * 2);
    unsigned short* zb  = (unsigned short*)alloc((size_t)N_NODES * DIM * 2);
    unsigned short* featb = (unsigned short*)alloc((size_t)N_NODES * DIM * 2);
    float* el    = (float*)alloc((size_t)N_NODES * HEADS * 4);
    float* er    = (float*)alloc((size_t)N_NODES * HEADS * 4);
    unsigned short* y1b = (unsigned short*)alloc((size_t)N_NODES * 224 * 2);
    unsigned short* btb = (unsigned short*)alloc((size_t)N_NODES * DIM * 2);
    int*   counts= (int*)  alloc((size_t)N_NODES * 4);          // contiguous with statsAll
    float* statsAll = (float*)alloc(((size_t)3 * NREP * 256 + 7 * 256) * 4);
    unsigned short* wpk = (unsigned short*)alloc((size_t)WPK_TOT * 2);
    int*   indptr= (int*)  alloc((size_t)(N_NODES + 1) * 4);
    int*   cursor= (int*)  alloc((size_t)N_NODES * 4);
    int*   srcs_csr = (int*)alloc((size_t)N_EDGES * 4);
    (void)ws_size; (void)in_sizes; (void)n_in; (void)out_size;

    float* rep1   = statsAll;                              // + l*NREP*256
    float* stats1c= statsAll + 3 * NREP * 256;             // + l*256
    float* stats2 = statsAll + 3 * NREP * 256 + 3 * 256;   // + l*256
    float* statsD = statsAll + 3 * NREP * 256 + 6 * 256;

    dim3 ggs((N_NODES + 31) / 32, 2);   // split-K: 32-row tiles, 2 col-groups

    hipMemsetAsync(counts, 0, (size_t)N_NODES * 4 + ((size_t)3 * NREP * 256 + 7 * 256) * 4, stream);
    hist_pack_kernel<<<HIST_BLOCKS + PACK_BLOCKS, 256, 0, stream>>>(
        dst, counts, W_emb, gat_W, ff_W1, ff_W2, dec_W1, wpk);
    scan_kernel<<<1, 1024, 0, stream>>>(counts, indptr, cursor, N_NODES);
    scatter_kernel<<<(N_EDGES + 255) / 256, 256, 0, stream>>>(src, dst, cursor, srcs_csr);

    // embed: xsb[:,0:128] = x @ W_emb + b_emb  (fp32 A, K=64)
    gemm_sk_kernel<4, 64, 0, false, false, false><<<ggs, 256, 0, stream>>>(
        x, nullptr, IN_DIM, wpk + OFF_EMB, b_emb,
        nullptr, 0, nullptr, nullptr, nullptr,
        nullptr, xsb, 512, nullptr,
        N_NODES, DIM, 0, nullptr, nullptr, nullptr, nullptr,
        nullptr, nullptr, nullptr, nullptr);

    for (int l = 0; l < LAYERS; l++) {
        const unsigned short* h_cur = xsb + (size_t)l * DIM;
        const float* hstats = l ? stats2 + (l - 1) * 256 : nullptr;
        const float* hg = l ? bn2_g + (l - 1) * DIM : nullptr;
        const float* hb = l ? bn2_b + (l - 1) * DIM : nullptr;
        // feat = BN2(h) @ gat_W -> bf16, fused el/er
        if (l == 0)
            gemm_sk_kernel<4, 128, 0, true, true, false><<<ggs, 256, 0, stream>>>(
                nullptr, h_cur, 512, wpk + OFF_GAT + l * 16384, nullptr,
                nullptr, 0, nullptr, nullptr, nullptr,
                nullptr, featb, DIM, nullptr,
                N_NODES, DIM, 0, nullptr, nullptr, nullptr, nullptr,
                attn_l + l * DIM, attn_r + l * DIM, el, er);
        else
            gemm_sk_kernel<4, 128, 1, true, true, false><<<ggs, 256, 0, stream>>>(
                nullptr, h_cur, 512, wpk + OFF_GAT + l * 16384, nullptr,
                nullptr, 0, nullptr, nullptr, nullptr,
                nullptr, featb, DIM, nullptr,
                N_NODES, DIM, 0, hstats, nullptr, hg, hb,
                attn_l + l * DIM, attn_r + l * DIM, el, er);
        // btb = BN2(h) + agg + bias  (pre-BN1, bf16); inline edge exp; fused BN1 rep-stats
        gat_aggregate_kernel<<<N_NODES, 256, 0, stream>>>(
            featb, el, er, indptr, srcs_csr, h_cur, 512,
            hstats, hg, hb, gat_b + l * DIM, btb,
            rep1 + (size_t)l * NREP * 256);
        // FFN1: y1 = relu(BN1(btb) @ W1 + b1) -> bf16 ld224; AMODE=3 sums replicas
        gemm_sk_kernel<7, 128, 3, true, false, false><<<ggs, 256, 0, stream>>>(
            nullptr, btb, DIM, wpk + OFF_W1 + l * 28672,
            ff_b1 + l * FF_DIM,
            nullptr, 0, nullptr, nullptr, nullptr,
            nullptr, y1b, 224, nullptr,
            N_NODES, FF_DIM, 1,
            rep1 + (size_t)l * NREP * 256, stats1c + l * 256,
            bn1_g + l * DIM, bn1_b + l * DIM,
            nullptr, nullptr, nullptr, nullptr);
        // FFN2: t = y1 @ W2 + b2 + BN1(btb) -> xsb block l+1 (bf16) + bn2 stats
        gemm_sk_kernel<4, 224, 0, true, false, true><<<ggs, 256, 0, stream>>>(
            nullptr, y1b, 224, wpk + OFF_W2 + l * 28672,
            ff_b2 + l * DIM,
            btb, DIM, stats1c + l * 256, bn1_g + l * DIM, bn1_b + l * DIM,
            nullptr, xsb + (size_t)(l + 1) * DIM, 512, stats2 + l * 256,
            N_NODES, DIM, 0, nullptr, nullptr, nullptr, nullptr,
            nullptr, nullptr, nullptr, nullptr);
    }

    // dec: z = BN-affine-concat(xsb) @ dec_W1 (bf16 out) + dec stats
    gemm_sk_kernel<4, 512, 2, true, false, false><<<ggs, 256, 0, stream>>>(
        nullptr, xsb, 512, wpk + OFF_DEC, nullptr,
        nullptr, 0, nullptr, nullptr, nullptr,
        nullptr, zb, DIM, statsD,
        N_NODES, DIM, 0, stats2, nullptr, bn2_g, bn2_b,
        nullptr, nullptr, nullptr, nullptr);
    decide_kernel<<<(N_NODES + 3) / 4, 256, 0, stream>>>(
        zb, statsD, dec_bn_g, dec_bn_b, dec_W2, outp, N_NODES);
}

// Round 19
// 780.846 us; speedup vs baseline: 1.4934x; 1.4934x over previous
//
#include <hip/hip_runtime.h>
#include <hip/hip_bf16.h>
#include <math.h>

#define N_NODES 40000
#define N_EDGES 640000
#define DIM     128
#define HEADS   8
#define DHEAD   16
#define LAYERS  3
#define IN_DIM  64
#define FF_DIM  218
#define BN_EPS  1e-5f
#define NEG_SLOPE 0.2f
#define INV_N   (1.f / N_NODES)
#define NREP    128

typedef __attribute__((ext_vector_type(8))) short  bhalf8;
typedef __attribute__((ext_vector_type(4))) float  floatx4;
typedef __attribute__((ext_vector_type(4))) int    intx4;

__device__ __forceinline__ unsigned bfpack2(float a, float b) {
    unsigned ua = __float_as_uint(a);
    ua = ua + 0x7FFFu + ((ua >> 16) & 1u);
    unsigned ub = __float_as_uint(b);
    ub = ub + 0x7FFFu + ((ub >> 16) & 1u);
    return (ua >> 16) | (ub & 0xFFFF0000u);
}
__device__ __forceinline__ unsigned short bf16of(float a) {
    unsigned ua = __float_as_uint(a);
    ua = ua + 0x7FFFu + ((ua >> 16) & 1u);
    return (unsigned short)(ua >> 16);
}
__device__ __forceinline__ float bf2f(unsigned short u) {
    return __uint_as_float(((unsigned)u) << 16);
}
__device__ __forceinline__ float bflo(unsigned u) { return __uint_as_float(u << 16); }
__device__ __forceinline__ float bfhi(unsigned u) { return __uint_as_float(u & 0xFFFF0000u); }
__device__ __forceinline__ float rsum16(float v) {
    v += __shfl_xor(v, 1, 16);
    v += __shfl_xor(v, 2, 16);
    v += __shfl_xor(v, 4, 16);
    v += __shfl_xor(v, 8, 16);
    return v;
}

// packed weight layout offsets (bf16 elements)
#define OFF_EMB 0
#define OFF_GAT 8192
#define OFF_W1  57344
#define OFF_W2  143360
#define OFF_DEC 229376
#define WPK_TOT 294912
#define HIST_BLOCKS ((N_EDGES + 255) / 256)
#define PACK_BLOCKS ((WPK_TOT + 255) / 256)

// ---------------------------------------------------------------- hist + weight pre-pack (merged)
__global__ void hist_pack_kernel(const int* __restrict__ dst, int* __restrict__ counts,
                                 const float* __restrict__ W_emb,
                                 const float* __restrict__ gat_W,
                                 const float* __restrict__ ff_W1,
                                 const float* __restrict__ ff_W2,
                                 const float* __restrict__ dec_W1,
                                 unsigned short* __restrict__ wpk) {
    int bid = blockIdx.x;
    if (bid < HIST_BLOCKS) {
        int e = bid * 256 + threadIdx.x;
        if (e < N_EDGES) atomicAdd(&counts[dst[e]], 1);
        return;
    }
    int i = (bid - HIST_BLOCKS) * 256 + threadIdx.x;
    if (i >= WPK_TOT) return;
    int o = i;
    if (o < 8192) {                       // emb: [128][64]
        int n = o >> 6, k = o & 63;
        wpk[OFF_EMB + o] = bf16of(W_emb[k * 128 + n]);
        return;
    }
    o -= 8192;
    if (o < 3 * 16384) {                  // gat: [l][128][128]
        int l = o >> 14, r = o & 16383;
        int n = r >> 7, k = r & 127;
        wpk[OFF_GAT + o] = bf16of(gat_W[l * 16384 + k * 128 + n]);
        return;
    }
    o -= 3 * 16384;
    if (o < 3 * 28672) {                  // W1: [l][224][128]
        int l = o / 28672, r = o % 28672;
        int n = r >> 7, k = r & 127;
        float v = (n < FF_DIM) ? ff_W1[(size_t)l * 128 * FF_DIM + k * FF_DIM + n] : 0.f;
        wpk[OFF_W1 + o] = bf16of(v);
        return;
    }
    o -= 3 * 28672;
    if (o < 3 * 28672) {                  // W2: [l][128][224]
        int l = o / 28672, r = o % 28672;
        int n = r / 224, k = r % 224;
        float v = (k < FF_DIM) ? ff_W2[(size_t)l * FF_DIM * 128 + k * 128 + n] : 0.f;
        wpk[OFF_W2 + o] = bf16of(v);
        return;
    }
    o -= 3 * 28672;
    {                                     // dec: [128][512]
        int n = o >> 9, k = o & 511;
        wpk[OFF_DEC + o] = bf16of(dec_W1[k * 128 + n]);
    }
}

// ---------------------------------------------------------------- CSR build
__global__ __launch_bounds__(1024) void scan_kernel(const int* __restrict__ counts,
                                                    int* __restrict__ indptr,
                                                    int* __restrict__ cursor, int n) {
    __shared__ int tsum[1024];
    const int CH = 40;
    int tid = threadIdx.x;
    int base = tid * CH;
    int loc[CH];
    int s = 0;
    #pragma unroll
    for (int i = 0; i < CH; i++) {
        int idx = base + i;
        int v = (idx < n) ? counts[idx] : 0;
        loc[i] = s;
        s += v;
    }
    tsum[tid] = s;
    __syncthreads();
    for (int offs = 1; offs < 1024; offs <<= 1) {
        int t = (tid >= offs) ? tsum[tid - offs] : 0;
        __syncthreads();
        tsum[tid] += t;
        __syncthreads();
    }
    int carry = (tid > 0) ? tsum[tid - 1] : 0;
    #pragma unroll
    for (int i = 0; i < CH; i++) {
        int idx = base + i;
        if (idx < n) {
            int v = carry + loc[i];
            indptr[idx] = v;
            cursor[idx] = v;
        }
    }
    if (tid == 1023) indptr[n] = tsum[1023];
}

__global__ void scatter_kernel(const int* __restrict__ src, const int* __restrict__ dst,
                               int* __restrict__ cursor,
                               int* __restrict__ srcs_csr) {
    int e = blockIdx.x * blockDim.x + threadIdx.x;
    if (e < N_EDGES) {
        int d = dst[e];
        int pos = atomicAdd(&cursor[d], 1);
        srcs_csr[pos] = src[e];
    }
}

// ---------------------------------------------------------------- L2-resident-B GEMM
// Measured-best config over NT{2,4,8} x MT{1,2} x CST{1,2,4} x {split-K}:
// NT=4/7, MT=2, 2 col-groups, CST=2, no split-K.
// AMODE: 0 none; 1 BN affine on A; 2 dec512 layered affine; 3 NREP-replica stats.
template<int NT, int KPAD, int AMODE, bool ABF16, int MT, bool ELER, bool RESBF>
__global__ __launch_bounds__(256) void gemm_l2_kernel(
    const float* __restrict__ A, const unsigned short* __restrict__ Abf, int lda,
    const unsigned short* __restrict__ Bpk,
    const float* __restrict__ bias,
    const void* __restrict__ resv, int ldres,
    const float* __restrict__ res_stats, const float* __restrict__ res_g,
    const float* __restrict__ res_b,
    float* __restrict__ C, unsigned short* __restrict__ Cbf, int ldc,
    float* __restrict__ out_stats,
    int M, int Nact, int relu,
    const float* __restrict__ a_stats, float* __restrict__ a_stats_out,
    const float* __restrict__ a_g, const float* __restrict__ a_b,
    const float* __restrict__ al, const float* __restrict__ ar,
    float* __restrict__ el_out, float* __restrict__ er_out)
{
    constexpr int SCN = (AMODE > 0) ? KPAD : 1;
    constexpr int BROWS = 64 * MT;
    constexpr int STEPS = KPAD / 32;
    constexpr int CST = (STEPS > 2) ? 2 : STEPS;
    __shared__ float sc_s[SCN];
    __shared__ float sh_s[SCN];
    __shared__ float st_sum[128];
    __shared__ float st_sq[128];
    __shared__ float el_s[ELER ? BROWS : 1][ELER ? NT : 1];
    __shared__ float er_s[ELER ? BROWS : 1][ELER ? NT : 1];

    int tid = threadIdx.x, wave = tid >> 6, lane = tid & 63;
    int q = lane >> 4, tl = lane & 15;
    int colbase = blockIdx.y * (NT * 16);
    int row0b = blockIdx.x * BROWS;
    int rowtile = row0b + wave * (MT * 16);

    if constexpr (AMODE == 1 || AMODE == 2) {
        for (int idx = tid; idx < KPAD; idx += 256) {
            float scv = 1.f, shv = 0.f;
            if constexpr (AMODE == 1) {
                float mu = a_stats[idx] * INV_N;
                float var = a_stats[128 + idx] * INV_N - mu * mu;
                scv = a_g[idx] * rsqrtf(var + BN_EPS);
                shv = a_b[idx] - mu * scv;
            } else {
                int l = idx >> 7;
                if (l > 0) {
                    int c = idx & 127;
                    const float* st = a_stats + (l - 1) * 256;
                    float mu = st[c] * INV_N;
                    float var = st[128 + c] * INV_N - mu * mu;
                    scv = a_g[(l - 1) * 128 + c] * rsqrtf(var + BN_EPS);
                    shv = a_b[(l - 1) * 128 + c] - mu * scv;
                }
            }
            sc_s[idx] = scv;
            sh_s[idx] = shv;
        }
        __syncthreads();
    }
    if constexpr (AMODE == 3) {
        for (int idx = tid; idx < 128; idx += 256) {
            float s = 0.f, sq = 0.f;
            #pragma unroll 8
            for (int r = 0; r < NREP; r++) {
                s  += a_stats[r * 256 + idx];
                sq += a_stats[r * 256 + 128 + idx];
            }
            a_stats_out[idx] = s;            // benign identical-value race
            a_stats_out[128 + idx] = sq;
            float mu = s * INV_N;
            float var = sq * INV_N - mu * mu;
            float scv = a_g[idx] * rsqrtf(var + BN_EPS);
            sc_s[idx] = scv;
            sh_s[idx] = a_b[idx] - mu * scv;
        }
        __syncthreads();
    }

    int rowm[MT];
    bool vrm[MT];
    #pragma unroll
    for (int mt = 0; mt < MT; mt++) {
        rowm[mt] = rowtile + mt * 16 + tl;
        vrm[mt] = rowm[mt] < M;
    }
    const unsigned short* bp = Bpk + (size_t)colbase * KPAD;

    floatx4 acc[MT][NT] = {};

    #pragma unroll
    for (int c0 = 0; c0 < STEPS; c0 += CST) {
        intx4  arawb[CST][MT];
        floatx4 araw0[ABF16 ? 1 : CST][ABF16 ? 1 : MT];
        floatx4 araw1[ABF16 ? 1 : CST][ABF16 ? 1 : MT];
        bhalf8 breg[CST][NT];
        #pragma unroll
        for (int cs = 0; cs < CST; cs++) {
            if (c0 + cs >= STEPS) continue;
            int gk = (c0 + cs) * 32 + q * 8;
            #pragma unroll
            for (int j = 0; j < NT; j++)
                breg[cs][j] = *(const bhalf8*)(bp + (size_t)(j * 16 + tl) * KPAD + gk);
            #pragma unroll
            for (int mt = 0; mt < MT; mt++) {
                if constexpr (ABF16) {
                    intx4 u = {};
                    if (vrm[mt]) u = *(const intx4*)(Abf + (size_t)rowm[mt] * lda + gk);
                    arawb[cs][mt] = u;
                } else {
                    floatx4 x0 = {}, x1 = {};
                    if (vrm[mt]) {
                        const float* ap = A + (size_t)rowm[mt] * lda + gk;
                        x0 = *(const floatx4*)ap;
                        x1 = *(const floatx4*)(ap + 4);
                    }
                    araw0[cs][mt] = x0;
                    araw1[cs][mt] = x1;
                }
            }
        }
        #pragma unroll
        for (int cs = 0; cs < CST; cs++) {
            if (c0 + cs >= STEPS) continue;
            int gk = (c0 + cs) * 32 + q * 8;
            bhalf8 af[MT];
            #pragma unroll
            for (int mt = 0; mt < MT; mt++) {
                if constexpr (ABF16) {
                    intx4 u = arawb[cs][mt];
                    if constexpr (AMODE > 0) {
                        #pragma unroll
                        for (int w = 0; w < 4; w++) {
                            unsigned uw = (unsigned)u[w];
                            float lo = bflo(uw), hi = bfhi(uw);
                            lo = fmaf(sc_s[gk + 2 * w],     lo, sh_s[gk + 2 * w]);
                            hi = fmaf(sc_s[gk + 2 * w + 1], hi, sh_s[gk + 2 * w + 1]);
                            u[w] = (int)bfpack2(lo, hi);
                        }
                    }
                    af[mt] = *(bhalf8*)&u;
                } else {
                    floatx4 x0 = araw0[cs][mt], x1 = araw1[cs][mt];
                    if constexpr (AMODE > 0) {
                        #pragma unroll
                        for (int jj = 0; jj < 4; jj++) {
                            x0[jj] = fmaf(sc_s[gk + jj],     x0[jj], sh_s[gk + jj]);
                            x1[jj] = fmaf(sc_s[gk + 4 + jj], x1[jj], sh_s[gk + 4 + jj]);
                        }
                    }
                    intx4 t = intx4{(int)bfpack2(x0[0], x0[1]), (int)bfpack2(x0[2], x0[3]),
                                    (int)bfpack2(x1[0], x1[1]), (int)bfpack2(x1[2], x1[3])};
                    af[mt] = *(bhalf8*)&t;
                }
            }
            #pragma unroll
            for (int mt = 0; mt < MT; mt++)
                #pragma unroll
                for (int j = 0; j < NT; j++)
                    acc[mt][j] = __builtin_amdgcn_mfma_f32_16x16x32_bf16(af[mt], breg[cs][j], acc[mt][j], 0, 0, 0);
        }
    }

    // epilogue: C/D layout col=lane&15, row=quad*4+reg
    float psum[NT], psq[NT];
    #pragma unroll
    for (int j = 0; j < NT; j++) { psum[j] = 0.f; psq[j] = 0.f; }

    #pragma unroll
    for (int j = 0; j < NT; j++) {
        int c = colbase + j * 16 + tl;
        bool cok = c < Nact;
        float bv = (bias && cok) ? bias[c] : 0.f;
        float rsc = 1.f, rsh = 0.f;
        if (res_stats && cok) {
            float mu = res_stats[c] * INV_N;
            float var = res_stats[128 + c] * INV_N - mu * mu;
            rsc = res_g[c] * rsqrtf(var + BN_EPS);
            rsh = res_b[c] - mu * rsc;
        }
        float alc = 0.f, arc = 0.f;
        if constexpr (ELER) { alc = al[c]; arc = ar[c]; }
        #pragma unroll
        for (int mt = 0; mt < MT; mt++) {
            #pragma unroll
            for (int reg = 0; reg < 4; reg++) {
                int r = rowtile + mt * 16 + q * 4 + reg;
                bool rok = r < M;
                float v = 0.f;
                if (rok && cok) {
                    v = acc[mt][j][reg] + bv;
                    if (resv) {
                        size_t ri = (size_t)r * ldres + c;
                        float rv = RESBF ? bf2f(((const unsigned short*)resv)[ri])
                                         : ((const float*)resv)[ri];
                        v = fmaf(rsc, rv, v + rsh);
                    }
                    if (relu) v = fmaxf(v, 0.f);
                    if (out_stats) { psum[j] += v; psq[j] = fmaf(v, v, psq[j]); }
                }
                if constexpr (ELER) {
                    float pel = rsum16(v * alc);
                    float per_ = rsum16(v * arc);
                    if (tl == 0) {
                        int rl = wave * (MT * 16) + mt * 16 + q * 4 + reg;
                        el_s[rl][j] = pel;
                        er_s[rl][j] = per_;
                    }
                }
                if (rok) {
                    if (Cbf) Cbf[(size_t)r * ldc + c] = bf16of(v);
                    else if (cok) C[(size_t)r * ldc + c] = v;
                }
            }
        }
    }

    if constexpr (ELER) {
        __syncthreads();
        int gh = blockIdx.y * NT;
        for (int idx = tid; idx < BROWS * NT; idx += 256) {
            int rl = idx / NT, hj = idx % NT;
            int r = row0b + rl;
            if (r < M) {
                el_out[(size_t)r * 8 + gh + hj] = el_s[rl][hj];
                er_out[(size_t)r * 8 + gh + hj] = er_s[rl][hj];
            }
        }
    }

    if (out_stats) {
        __syncthreads();
        if (tid < 128) { st_sum[tid] = 0.f; st_sq[tid] = 0.f; }
        __syncthreads();
        #pragma unroll
        for (int j = 0; j < NT; j++) {
            int c = colbase + j * 16 + tl;
            if (c < 128) { atomicAdd(&st_sum[c], psum[j]); atomicAdd(&st_sq[c], psq[j]); }
        }
        __syncthreads();
        if (tid < 128) {
            atomicAdd(&out_stats[tid], st_sum[tid]);
            atomicAdd(&out_stats[128 + tid], st_sq[tid]);
        }
    }
}

// ---------------------------------------------------------------- GAT aggregate
// Measured-best structure: 1 node/block, 4 edge-groups x 4-unroll = 16 gathers in
// flight; shfl-dedup exp; fused BN1 stats into NREP-replica buffers.
__global__ __launch_bounds__(256) void gat_aggregate_kernel(
    const unsigned short* __restrict__ feat,
    const float* __restrict__ el, const float* __restrict__ er,
    const int* __restrict__ indptr, const int* __restrict__ srcs_csr,
    const unsigned short* __restrict__ h_in, int ldh,
    const float* __restrict__ hstats, const float* __restrict__ hg,
    const float* __restrict__ hb,
    const float* __restrict__ bias,
    unsigned short* __restrict__ outp,
    float* __restrict__ stats_rep)
{
    int n = blockIdx.x;
    int t = threadIdx.x;
    int p = t >> 6;
    int lane = t & 63;
    int d0 = lane * 2;
    int hh = lane >> 3;
    int pick = lane & 3;
    int gb = lane & 56;
    __shared__ float red[4][128];
    __shared__ float denh[4][HEADS];
    int beg = indptr[n], end = indptr[n + 1];
    float ern = er[(size_t)n * 8 + hh];

    float acc0 = 0.f, acc1 = 0.f, den = 0.f;
    int i = beg + p;
    for (; i + 12 < end; i += 16) {
        int s0 = srcs_csr[i],     s1 = srcs_csr[i + 4];
        int s2 = srcs_csr[i + 8], s3 = srcs_csr[i + 12];
        int sp = pick == 0 ? s0 : pick == 1 ? s1 : pick == 2 ? s2 : s3;
        float ee = el[(size_t)sp * 8 + hh] + ern;
        unsigned f0 = *(const unsigned*)(feat + (size_t)s0 * DIM + d0);
        unsigned f1 = *(const unsigned*)(feat + (size_t)s1 * DIM + d0);
        unsigned f2 = *(const unsigned*)(feat + (size_t)s2 * DIM + d0);
        unsigned f3 = *(const unsigned*)(feat + (size_t)s3 * DIM + d0);
        float aa = expf(ee > 0.f ? ee : NEG_SLOPE * ee);
        float a0 = __shfl(aa, gb + 0);
        float a1 = __shfl(aa, gb + 1);
        float a2 = __shfl(aa, gb + 2);
        float a3 = __shfl(aa, gb + 3);
        den += (a0 + a1) + (a2 + a3);
        acc0 = fmaf(a0, bflo(f0), acc0); acc1 = fmaf(a0, bfhi(f0), acc1);
        acc0 = fmaf(a1, bflo(f1), acc0); acc1 = fmaf(a1, bfhi(f1), acc1);
        acc0 = fmaf(a2, bflo(f2), acc0); acc1 = fmaf(a2, bfhi(f2), acc1);
        acc0 = fmaf(a3, bflo(f3), acc0); acc1 = fmaf(a3, bfhi(f3), acc1);
    }
    for (; i < end; i += 4) {
        int s0 = srcs_csr[i];
        float e0 = el[(size_t)s0 * 8 + hh] + ern;
        unsigned f0 = *(const unsigned*)(feat + (size_t)s0 * DIM + d0);
        float a0 = expf(e0 > 0.f ? e0 : NEG_SLOPE * e0);
        den += a0;
        acc0 = fmaf(a0, bflo(f0), acc0);
        acc1 = fmaf(a0, bfhi(f0), acc1);
    }
    red[p][d0] = acc0;
    red[p][d0 + 1] = acc1;
    if ((lane & 7) == 0) denh[p][hh] = den;
    __syncthreads();
    if (t < 128) {
        int d = t, h = d >> 4;
        float tot = (red[0][d] + red[1][d]) + (red[2][d] + red[3][d]);
        float dtot = (denh[0][h] + denh[1][h]) + (denh[2][h] + denh[3][h]);
        float inv = dtot > 0.f ? 1.f / dtot : 0.f;
        float hv = bf2f(h_in[(size_t)n * ldh + d]);
        if (hstats) {
            float mu = hstats[d] * INV_N;
            float var = hstats[128 + d] * INV_N - mu * mu;
            float s = hg[d] * rsqrtf(var + BN_EPS);
            hv = fmaf(s, hv - mu, hb[d]);
        }
        unsigned short ub = bf16of(hv + tot * inv + bias[d]);
        outp[(size_t)n * DIM + d] = ub;
        float vr = bf2f(ub);
        float* rep = stats_rep + ((size_t)(n & (NREP - 1)) << 8);
        atomicAdd(&rep[d], vr);
        atomicAdd(&rep[128 + d], vr * vr);
    }
}

// ---------------------------------------------------------------- decision head
__global__ __launch_bounds__(256) void decide_kernel(
    const unsigned short* __restrict__ z, const float* __restrict__ stats,
    const float* __restrict__ g, const float* __restrict__ b,
    const float* __restrict__ W2, float* __restrict__ outp, int M)
{
    int wid = threadIdx.x >> 6, lane = threadIdx.x & 63;
    int n = blockIdx.x * 4 + wid;
    if (n >= M) return;
    float acc = 0.f;
    #pragma unroll
    for (int cc = 0; cc < 2; cc++) {
        int c = lane + cc * 64;
        float mu  = stats[c] * INV_N;
        float var = stats[DIM + c] * INV_N - mu * mu;
        float v = fmaf(g[c] * rsqrtf(var + BN_EPS), bf2f(z[(size_t)n * DIM + c]) - mu, b[c]);
        v = fmaxf(v, 0.f);
        acc = fmaf(v, W2[c], acc);
    }
    #pragma unroll
    for (int offs = 32; offs > 0; offs >>= 1)
        acc += __shfl_down(acc, offs);
    if (lane == 0) outp[n] = acc;
}

// ---------------------------------------------------------------- launch
extern "C" void kernel_launch(void* const* d_in, const int* in_sizes, int n_in,
                              void* d_out, int out_size, void* d_ws, size_t ws_size,
                              hipStream_t stream)
{
    const float* x      = (const float*)d_in[0];
    const int*   src    = (const int*)  d_in[1];
    const int*   dst    = (const int*)  d_in[2];
    const float* W_emb  = (const float*)d_in[3];
    const float* b_emb  = (const float*)d_in[4];
    const float* gat_W  = (const float*)d_in[5];
    const float* attn_l = (const float*)d_in[6];
    const float* attn_r = (const float*)d_in[7];
    const float* gat_b  = (const float*)d_in[8];
    const float* bn1_g  = (const float*)d_in[9];
    const float* bn1_b  = (const float*)d_in[10];
    const float* ff_W1  = (const float*)d_in[11];
    const float* ff_b1  = (const float*)d_in[12];
    const float* ff_W2  = (const float*)d_in[13];
    const float* ff_b2  = (const float*)d_in[14];
    const float* bn2_g  = (const float*)d_in[15];
    const float* bn2_b  = (const float*)d_in[16];
    const float* dec_W1 = (const float*)d_in[17];
    const float* dec_bn_g = (const float*)d_in[18];
    const float* dec_bn_b = (const float*)d_in[19];
    const float* dec_W2 = (const float*)d_in[20];
    float* outp = (float*)d_out;

    char* ws = (char*)d_ws;
    size_t off = 0;
    auto alloc = [&](size_t bytes) -> void* {
        void* p = ws + off;
        off += (bytes + 255) & ~(size_t)255;
        return p;
    };
    unsigned short* xsb = (unsigned short*)alloc((size_t)N_NODES * 512 * 2);
    unsigned short* zb  = (unsigned short*)alloc((size_t)N_NODES * DIM * 2);
    unsigned short* featb = (unsigned short*)alloc((size_t)N_NODES * DIM * 2);
    float* el    = (float*)alloc((size_t)N_NODES * HEADS * 4);
    float* er    = (float*)alloc((size_t)N_NODES * HEADS * 4);
    unsigned short* y1b = (unsigned short*)alloc((size_t)N_NODES * 224 * 2);
    unsigned short* btb = (unsigned short*)alloc((size_t)N_NODES * DIM * 2);
    int*   counts= (int*)  alloc((size_t)N_NODES * 4);          // contiguous with statsAll
    float* statsAll = (float*)alloc(((size_t)3 * NREP * 256 + 7 * 256) * 4);
    unsigned short* wpk = (unsigned short*)alloc((size_t)WPK_TOT * 2);
    int*   indptr= (int*)  alloc((size_t)(N_NODES + 1) * 4);
    int*   cursor= (int*)  alloc((size_t)N_NODES * 4);
    int*   srcs_csr = (int*)alloc((size_t)N_EDGES * 4);
    (void)ws_size; (void)in_sizes; (void)n_in; (void)out_size;

    float* rep1   = statsAll;                              // + l*NREP*256
    float* stats1c= statsAll + 3 * NREP * 256;             // + l*256
    float* stats2 = statsAll + 3 * NREP * 256 + 3 * 256;   // + l*256
    float* statsD = statsAll + 3 * NREP * 256 + 6 * 256;

    dim3 gg2((N_NODES + 127) / 128, 2);   // NT=4 (or 7), MT=2: 2 col-groups

    hipMemsetAsync(counts, 0, (size_t)N_NODES * 4 + ((size_t)3 * NREP * 256 + 7 * 256) * 4, stream);
    hist_pack_kernel<<<HIST_BLOCKS + PACK_BLOCKS, 256, 0, stream>>>(
        dst, counts, W_emb, gat_W, ff_W1, ff_W2, dec_W1, wpk);
    scan_kernel<<<1, 1024, 0, stream>>>(counts, indptr, cursor, N_NODES);
    scatter_kernel<<<(N_EDGES + 255) / 256, 256, 0, stream>>>(src, dst, cursor, srcs_csr);

    // embed: xsb[:,0:128] = x @ W_emb + b_emb  (fp32 A, K=64)
    gemm_l2_kernel<4, 64, 0, false, 2, false, false><<<gg2, 256, 0, stream>>>(
        x, nullptr, IN_DIM, wpk + OFF_EMB, b_emb,
        nullptr, 0, nullptr, nullptr, nullptr,
        nullptr, xsb, 512, nullptr,
        N_NODES, DIM, 0, nullptr, nullptr, nullptr, nullptr,
        nullptr, nullptr, nullptr, nullptr);

    for (int l = 0; l < LAYERS; l++) {
        const unsigned short* h_cur = xsb + (size_t)l * DIM;
        const float* hstats = l ? stats2 + (l - 1) * 256 : nullptr;
        const float* hg = l ? bn2_g + (l - 1) * DIM : nullptr;
        const float* hb = l ? bn2_b + (l - 1) * DIM : nullptr;
        // feat = BN2(h) @ gat_W -> bf16, fused el/er
        if (l == 0)
            gemm_l2_kernel<4, 128, 0, true, 2, true, false><<<gg2, 256, 0, stream>>>(
                nullptr, h_cur, 512, wpk + OFF_GAT + l * 16384, nullptr,
                nullptr, 0, nullptr, nullptr, nullptr,
                nullptr, featb, DIM, nullptr,
                N_NODES, DIM, 0, nullptr, nullptr, nullptr, nullptr,
                attn_l + l * DIM, attn_r + l * DIM, el, er);
        else
            gemm_l2_kernel<4, 128, 1, true, 2, true, false><<<gg2, 256, 0, stream>>>(
                nullptr, h_cur, 512, wpk + OFF_GAT + l * 16384, nullptr,
                nullptr, 0, nullptr, nullptr, nullptr,
                nullptr, featb, DIM, nullptr,
                N_NODES, DIM, 0, hstats, nullptr, hg, hb,
                attn_l + l * DIM, attn_r + l * DIM, el, er);
        // btb = BN2(h) + agg + bias  (pre-BN1, bf16); inline edge exp; fused BN1 rep-stats
        gat_aggregate_kernel<<<N_NODES, 256, 0, stream>>>(
            featb, el, er, indptr, srcs_csr, h_cur, 512,
            hstats, hg, hb, gat_b + l * DIM, btb,
            rep1 + (size_t)l * NREP * 256);
        // FFN1: y1 = relu(BN1(btb) @ W1 + b1) -> bf16 ld224; AMODE=3 sums replicas
        gemm_l2_kernel<7, 128, 3, true, 2, false, false><<<gg2, 256, 0, stream>>>(
            nullptr, btb, DIM, wpk + OFF_W1 + l * 28672,
            ff_b1 + l * FF_DIM,
            nullptr, 0, nullptr, nullptr, nullptr,
            nullptr, y1b, 224, nullptr,
            N_NODES, FF_DIM, 1,
            rep1 + (size_t)l * NREP * 256, stats1c + l * 256,
            bn1_g + l * DIM, bn1_b + l * DIM,
            nullptr, nullptr, nullptr, nullptr);
        // FFN2: t = y1 @ W2 + b2 + BN1(btb) -> xsb block l+1 (bf16) + bn2 stats
        gemm_l2_kernel<4, 224, 0, true, 2, false, true><<<gg2, 256, 0, stream>>>(
            nullptr, y1b, 224, wpk + OFF_W2 + l * 28672,
            ff_b2 + l * DIM,
            btb, DIM, stats1c + l * 256, bn1_g + l * DIM, bn1_b + l * DIM,
            nullptr, xsb + (size_t)(l + 1) * DIM, 512, stats2 + l * 256,
            N_NODES, DIM, 0, nullptr, nullptr, nullptr, nullptr,
            nullptr, nullptr, nullptr, nullptr);
    }

    // dec: z = BN-affine-concat(xsb) @ dec_W1 (bf16 out) + dec stats
    gemm_l2_kernel<4, 512, 2, true, 2, false, false><<<gg2, 256, 0, stream>>>(
        nullptr, xsb, 512, wpk + OFF_DEC, nullptr,
        nullptr, 0, nullptr, nullptr, nullptr,
        nullptr, zb, DIM, statsD,
        N_NODES, DIM, 0, stats2, nullptr, bn2_g, bn2_b,
        nullptr, nullptr, nullptr, nullptr);
    decide_kernel<<<(N_NODES + 3) / 4, 256, 0, stream>>>(
        zb, statsD, dec_bn_g, dec_bn_b, dec_W2, outp, N_NODES);
}